// Round 12
// baseline (205.193 us; speedup 1.0000x reference)
//
#include <hip/hip_runtime.h>
#include <hip/hip_bf16.h>

// B=2, T=2048, C=1024, NH=16, HD=64. fp32 I/O, bf16/f16 MFMA internals.
#define B_   2
#define T_   2048
#define C_   1024
#define NH_  16
#define HD_  64

typedef __attribute__((ext_vector_type(8))) short short8;       // 8 bf16 (MFMA A/B frag, K=32)
typedef __attribute__((ext_vector_type(4))) float float4_;      // MFMA C/D frag
typedef __attribute__((ext_vector_type(4))) _Float16 half4_;    // f16 MFMA A/B frag, K=16
typedef __attribute__((ext_vector_type(2))) __fp16  fp16x2;     // cvt_pkrtz native type
typedef __attribute__((ext_vector_type(4))) unsigned short ushort4_;

static __device__ __forceinline__ unsigned short f2bf(float f) {
    union { float f; unsigned u; } v; v.f = f;
    unsigned r = v.u + 0x7fffu + ((v.u >> 16) & 1u);   // RNE
    return (unsigned short)(r >> 16);
}

// async global->LDS, 16B per lane: lane i lands at (wave-uniform base) + i*16B.
static __device__ __forceinline__ void g2l16(const void* g, void* l) {
    __builtin_amdgcn_global_load_lds(
        (const __attribute__((address_space(1))) void*)g,
        (__attribute__((address_space(3))) void*)l, 16, 0, 0);
}

// ---------------------------------------------------------------------------
// prep: (1) x fp32->bf16 flat convert [blocks 0..2047], (2) w_attn T+convert
// [next 16*48], (3) w_proj T+convert [next 16*16]. 64x64 tiles, R=1024.
// ---------------------------------------------------------------------------
__global__ __launch_bounds__(256) void prep(
    const float* __restrict__ x,      unsigned short* __restrict__ xb,
    const float* __restrict__ wA,     unsigned short* __restrict__ wTa,
    const float* __restrict__ wP,     unsigned short* __restrict__ wTp)
{
    const int t = threadIdx.x;
    int blk = blockIdx.x;
    if (blk < 2048) {                  // flat convert: 8 elems/thread
        int i = blk * 256 + t;
        const float4* p = (const float4*)x + (size_t)i * 2;
        float4 a = p[0], b = p[1];
        short8 o;
        o[0]=f2bf(a.x); o[1]=f2bf(a.y); o[2]=f2bf(a.z); o[3]=f2bf(a.w);
        o[4]=f2bf(b.x); o[5]=f2bf(b.y); o[6]=f2bf(b.z); o[7]=f2bf(b.w);
        *((short8*)xb + i) = o;
        return;
    }
    blk -= 2048;
    const float* in; unsigned short* out; int Cc;
    if (blk < 16 * 48) { in = wA; out = wTa; Cc = 3072; }
    else               { blk -= 16 * 48; in = wP; out = wTp; Cc = 1024; }
    const int r0 = (blk % 16) * 64, c0 = (blk / 16) * 64;
    const int R = 1024;
    __shared__ __align__(16) unsigned short Ts[64][72];
    #pragma unroll
    for (int cc = 0; cc < 2; ++cc) {
        int c = cc * 256 + t;
        int r = c >> 3, col = (c & 7) * 8;
        const float* p = in + (size_t)(r0 + r) * Cc + c0 + col;
        #pragma unroll
        for (int i = 0; i < 8; ++i) Ts[col + i][r] = f2bf(p[i]);
    }
    __syncthreads();
    #pragma unroll
    for (int cc = 0; cc < 2; ++cc) {
        int c = cc * 256 + t;
        int cr = c >> 3, oc = (c & 7) * 8;
        uint4 v = *(const uint4*)(&Ts[cr][oc]);
        *(uint4*)(out + (size_t)(c0 + cr) * R + r0 + oc) = v;
    }
}

// ---------------------------------------------------------------------------
// m97-structure GEMM: C[M,N] = A[M,K] @ Bt[N,K]^T, bf16 in, fp32 accum.
// WRITE_VT: v-part columns (>= 2C) write ONLY transposed f16 V into
// vt[b*1024 + (col-2C)][token] (attn never reads qkv's v-part).
// ---------------------------------------------------------------------------
template <bool C_F32, int BM, bool WRITE_VT>
__global__ __launch_bounds__(256) void gemm_bt(
    const unsigned short* __restrict__ A,
    const unsigned short* __restrict__ Bt,
    void* __restrict__ Cv, unsigned short* __restrict__ vt,
    int M, int N, int K)
{
    __shared__ __align__(16) unsigned short As[BM * 32];
    __shared__ __align__(16) unsigned short Bs[128 * 32];
    const int t = threadIdx.x, lane = t & 63, w = t >> 6;
    const int quad = lane >> 4, ln = lane & 15;
    const int bm = blockIdx.x, bn = blockIdx.y;
    constexpr int NI = (BM == 128) ? 4 : 2;
    const int mw = (BM == 128) ? (w & 1) * 64 : 0;
    const int nw = (BM == 128) ? (w >> 1) * 64 : w * 32;
    float4_ acc[4][NI] = {};

    constexpr int AROWS = BM / 4;      // rows of A staged per wave
    const unsigned short* Ag = A  + (size_t)(bm * BM + w * AROWS + (lane >> 2)) * K + (lane & 3) * 8;
    const unsigned short* Bg = Bt + (size_t)(bn * 128 + w * 32 + (lane >> 2)) * K + (lane & 3) * 8;
    unsigned short* lA = &As[(w * AROWS) * 32 + lane * 8];
    unsigned short* lB = &Bs[(w * 32) * 32 + lane * 8];

    for (int k0 = 0; k0 < K; k0 += 32) {
        g2l16(Ag + k0, lA);
        if (BM == 128) g2l16(Ag + (size_t)16 * K + k0, lA + 16 * 32);
        g2l16(Bg + k0,                  lB);
        g2l16(Bg + (size_t)16 * K + k0, lB + 16 * 32);
        __syncthreads();
        short8 a[4], b[NI];
        #pragma unroll
        for (int i = 0; i < 4; ++i)
            a[i] = *(const short8*)(&As[(mw + i * 16 + ln) * 32 + quad * 8]);
        #pragma unroll
        for (int i = 0; i < NI; ++i)
            b[i] = *(const short8*)(&Bs[(nw + i * 16 + ln) * 32 + quad * 8]);
        #pragma unroll
        for (int mi = 0; mi < 4; ++mi)
            #pragma unroll
            for (int ni = 0; ni < NI; ++ni)
                acc[mi][ni] = __builtin_amdgcn_mfma_f32_16x16x32_bf16(
                    a[mi], b[ni], acc[mi][ni], 0, 0, 0);
        __syncthreads();
    }

    const int row0 = bm * BM + mw + quad * 4;
    const int col0 = bn * 128 + nw + ln;
    #pragma unroll
    for (int mi = 0; mi < 4; ++mi)
        #pragma unroll
        for (int ni = 0; ni < NI; ++ni) {
            bool isv = WRITE_VT && (col0 + ni * 16 >= 2 * C_);
            if (isv) {
                int d     = col0 + ni * 16 - 2 * C_;       // 0..1023
                int token = row0 + mi * 16;                // 4-aligned
                int b     = token >> 11, tloc = token & 2047;
                union { fp16x2 h2[2]; ushort4_ u4; } pk;
                pk.h2[0] = __builtin_amdgcn_cvt_pkrtz(acc[mi][ni][0], acc[mi][ni][1]);
                pk.h2[1] = __builtin_amdgcn_cvt_pkrtz(acc[mi][ni][2], acc[mi][ni][3]);
                *(ushort4_*)(vt + ((size_t)b * 1024 + d) * T_ + tloc) = pk.u4;
            } else {
                #pragma unroll
                for (int i = 0; i < 4; ++i) {
                    size_t idx = (size_t)(row0 + mi * 16 + i) * N + col0 + ni * 16;
                    if (C_F32) ((float*)Cv)[idx] = acc[mi][ni][i];
                    else       ((unsigned short*)Cv)[idx] = f2bf(acc[mi][ni][i]);
                }
            }
        }
}

// ---------------------------------------------------------------------------
// Flash attention, W=32, split-KV x2. Grid (16,32,2) = 1024 blocks = 4/CU.
// Block (qt,bh,s) processes kt in [s*16, s*16+16); fixed-shift softmax makes
// partials additive: y = (O0+O1)/(l0+l1). Partial O fp16, partial l fp32.
// ---------------------------------------------------------------------------
__global__ __launch_bounds__(256) void attn(
    const unsigned short* __restrict__ qkv,
    const unsigned short* __restrict__ vt,
    unsigned short* __restrict__ op,    // fp16, 2 planes of 4096*1024
    float* __restrict__ lp)             // fp32, [s][bh][q]
{
    __shared__ __align__(16) unsigned short Qs[128][72];  // bf16 [q][d]
    __shared__ __align__(16) unsigned short Ks[64][72];   // bf16 [kk][d]
    __shared__ __align__(16) unsigned short Vs[64][72];   // f16  [d][kk]

    const int t = threadIdx.x;
    const int qt = blockIdx.x, bh = blockIdx.y, s = blockIdx.z;
    const int b = bh >> 4, h = bh & 15;
    const int lane = t & 63, w = t >> 6;
    const int quad = lane >> 4, ln = lane & 15;

    const unsigned short* Qg  = qkv + (size_t)b * T_ * (3 * C_) + (size_t)h * HD_;
    const unsigned short* Kg  = Qg + C_ + (size_t)(s * (T_ / 2)) * (3 * C_);
    const unsigned short* Vtg = vt + (size_t)bh * HD_ * T_ + s * (T_ / 2);

    #pragma unroll
    for (int cc = 0; cc < 4; ++cc) {
        int c = cc * 256 + t;
        int r = c >> 3, col = (c & 7) * 8;
        *(uint4*)(&Qs[r][col]) = *(const uint4*)(Qg + (size_t)(qt * 128 + r) * (3 * C_) + col);
    }

    const int r0 = t >> 3, c0v = (t & 7) * 8;
    const int r1 = r0 + 32;

    uint4 kr0 = *(const uint4*)(Kg + (size_t)r0 * (3 * C_) + c0v);
    uint4 kr1 = *(const uint4*)(Kg + (size_t)r1 * (3 * C_) + c0v);
    uint4 vr0 = *(const uint4*)(Vtg + (size_t)r0 * T_ + c0v);
    uint4 vr1 = *(const uint4*)(Vtg + (size_t)r1 * T_ + c0v);

    __syncthreads();

    short8 qf[2][2];
    #pragma unroll
    for (int qm = 0; qm < 2; ++qm)
        #pragma unroll
        for (int dh = 0; dh < 2; ++dh)
            qf[qm][dh] = *(const short8*)(&Qs[w * 32 + qm * 16 + ln][dh * 32 + quad * 8]);

    float4_ ot[4][2] = {};
    float ls[2] = {0.f, 0.f};
    const float C1 = 0.125f * 1.44269504f;   // scale * log2(e)
    const float C2 = 8.0f * 1.44269504f;     // fixed shift * log2(e)

    for (int kt = 0; kt < T_ / 128; ++kt) {
        if (kt) __syncthreads();
        *(uint4*)(&Ks[r0][c0v]) = kr0;
        *(uint4*)(&Ks[r1][c0v]) = kr1;
        *(uint4*)(&Vs[r0][c0v]) = vr0;
        *(uint4*)(&Vs[r1][c0v]) = vr1;
        __syncthreads();

        if (kt + 1 < T_ / 128) {
            int kb = (kt + 1) * 64;
            kr0 = *(const uint4*)(Kg + (size_t)(kb + r0) * (3 * C_) + c0v);
            kr1 = *(const uint4*)(Kg + (size_t)(kb + r1) * (3 * C_) + c0v);
            vr0 = *(const uint4*)(Vtg + (size_t)r0 * T_ + kb + c0v);
            vr1 = *(const uint4*)(Vtg + (size_t)r1 * T_ + kb + c0v);
        }

        half4_ pf[4][2];
        #pragma unroll
        for (int ct = 0; ct < 4; ++ct) {
            short8 kb0 = *(const short8*)(&Ks[ct * 16 + ln][quad * 8]);
            short8 kb1 = *(const short8*)(&Ks[ct * 16 + ln][32 + quad * 8]);
            #pragma unroll
            for (int qm = 0; qm < 2; ++qm) {
                float4_ st = {};
                st = __builtin_amdgcn_mfma_f32_16x16x32_bf16(kb0, qf[qm][0], st, 0, 0, 0);
                st = __builtin_amdgcn_mfma_f32_16x16x32_bf16(kb1, qf[qm][1], st, 0, 0, 0);
                float p0 = __builtin_amdgcn_exp2f(st[0] * C1 - C2);
                float p1 = __builtin_amdgcn_exp2f(st[1] * C1 - C2);
                float p2 = __builtin_amdgcn_exp2f(st[2] * C1 - C2);
                float p3 = __builtin_amdgcn_exp2f(st[3] * C1 - C2);
                ls[qm] += (p0 + p1) + (p2 + p3);
                union { fp16x2 h2[2]; half4_ h4; } u;
                u.h2[0] = __builtin_amdgcn_cvt_pkrtz(p0, p1);
                u.h2[1] = __builtin_amdgcn_cvt_pkrtz(p2, p3);
                pf[ct][qm] = u.h4;
            }
        }

        #pragma unroll
        for (int dt = 0; dt < 4; ++dt)
            #pragma unroll
            for (int ct = 0; ct < 4; ++ct) {
                half4_ va = *(const half4_*)(&Vs[dt * 16 + ln][ct * 16 + quad * 4]);
                #pragma unroll
                for (int qm = 0; qm < 2; ++qm)
                    ot[dt][qm] = __builtin_amdgcn_mfma_f32_16x16x16f16(
                        va, pf[ct][qm], ot[dt][qm], 0, 0, 0);
            }
    }

    #pragma unroll
    for (int qm = 0; qm < 2; ++qm) {
        ls[qm] += __shfl_xor(ls[qm], 16, 64);
        ls[qm] += __shfl_xor(ls[qm], 32, 64);
    }

    #pragma unroll
    for (int qm = 0; qm < 2; ++qm) {
        int q = qt * 128 + w * 32 + qm * 16 + ln;            // 0..2047
        unsigned short* Or = op + (size_t)s * (4096 * 1024)
                           + ((size_t)b * T_ + q) * C_ + h * HD_;
        #pragma unroll
        for (int dt = 0; dt < 4; ++dt) {
            union { fp16x2 h2[2]; ushort4_ u4; } pk;
            pk.h2[0] = __builtin_amdgcn_cvt_pkrtz(ot[dt][qm][0], ot[dt][qm][1]);
            pk.h2[1] = __builtin_amdgcn_cvt_pkrtz(ot[dt][qm][2], ot[dt][qm][3]);
            *(ushort4_*)(Or + dt * 16 + quad * 4) = pk.u4;
        }
        if (quad == 0)
            lp[((size_t)s * (B_ * NH_) + bh) * T_ + q] = ls[qm];
    }
}

// ---------------------------------------------------------------------------
// merge: y = bf16( (O0+O1) / (l0+l1) ). 8 elems/thread (one h per thread).
// ---------------------------------------------------------------------------
__global__ __launch_bounds__(256) void merge(
    const unsigned short* __restrict__ op,
    const float* __restrict__ lp,
    unsigned short* __restrict__ y)
{
    const size_t i = ((size_t)blockIdx.x * 256 + threadIdx.x) * 8;
    const int row = (int)(i >> 10);            // b*T + q
    const int c   = (int)(i & 1023);
    const int b = row >> 11, q = row & 2047, h = c >> 6;
    const int bh = b * 16 + h;
    float l = lp[(size_t)bh * T_ + q] + lp[((size_t)B_ * NH_ + bh) * T_ + q];
    float inv = 1.0f / l;
    ushort4_ a0 = *(const ushort4_*)(op + i);
    ushort4_ a1 = *(const ushort4_*)(op + (size_t)4096 * 1024 + i);
    ushort4_ b0 = *(const ushort4_*)(op + i + 4);
    ushort4_ b1 = *(const ushort4_*)(op + (size_t)4096 * 1024 + i + 4);
    unsigned short o[8];
    #pragma unroll
    for (int j = 0; j < 4; ++j) {
        union { unsigned short u; __fp16 hh; } x0, x1, y0, y1;
        x0.u = a0[j]; x1.u = a1[j];
        y0.u = b0[j]; y1.u = b1[j];
        o[j]     = f2bf(((float)x0.hh + (float)x1.hh) * inv);
        o[j + 4] = f2bf(((float)y0.hh + (float)y1.hh) * inv);
    }
    *(ushort4_*)(y + i)     = *(ushort4_*)&o[0];
    *(ushort4_*)(y + i + 4) = *(ushort4_*)&o[4];
}

extern "C" void kernel_launch(void* const* d_in, const int* in_sizes, int n_in,
                              void* d_out, int out_size, void* d_ws, size_t ws_size,
                              hipStream_t stream)
{
    const float* x      = (const float*)d_in[0];   // [4096,1024]
    const float* w_attn = (const float*)d_in[1];   // [1024,3072]
    const float* w_proj = (const float*)d_in[2];   // [1024,1024]
    float* out = (float*)d_out;                    // [4096,1024]

    // ws (2B elems): qkv 12.58M | y/xb 4.19M | wTa 3.15M | wTp 1.05M |
    //                vt 4.19M | op 8.39M (2 planes) | lp 0.26M   (~67.7 MB)
    unsigned short* qkv = (unsigned short*)d_ws;
    unsigned short* y   = qkv + (size_t)4096 * 3072;   // xb before gemm1
    unsigned short* wTa = y   + (size_t)4096 * 1024;
    unsigned short* wTp = wTa + (size_t)3072 * 1024;
    unsigned short* vt  = wTp + (size_t)1024 * 1024;   // f16
    unsigned short* op  = vt  + (size_t)B_ * NH_ * HD_ * T_;   // 2 contiguous planes
    float* lp           = (float*)(op + (size_t)2 * 4096 * 1024);
    unsigned short* xb  = y;

    prep<<<2048 + 16 * 48 + 16 * 16, 256, 0, stream>>>(x, xb, w_attn, wTa, w_proj, wTp);

    gemm_bt<false, 128, true><<<dim3(32, 24), 256, 0, stream>>>(
        xb, wTa, qkv, vt, 4096, 3072, 1024);
    attn<<<dim3(16, 32, 2), 256, 0, stream>>>(qkv, vt, op, lp);
    merge<<<4096 * 1024 / 8 / 256, 256, 0, stream>>>(op, lp, y);

    gemm_bt<true, 64, false><<<dim3(64, 8), 256, 0, stream>>>(
        y, wTp, out, nullptr, 4096, 1024, 1024);
}